// Round 5
// baseline (330.440 us; speedup 1.0000x reference)
//
#include <hip/hip_runtime.h>
#include <hip/hip_fp16.h>

#define H 256
#define W 512
#define HW (H*W)
#define NPIXF 524288.0f
#define SPAN 11
#define KK 23
#define NBINS (KK*KK)   // 529

#define LOG2E 1.4426950408889634f
#define CEXP  (-0.7213475204444817f)   // -0.5*log2(e)
#define CRGB  (CEXP*100.0f)            // 1/SIG_RGB^2
#define CDEP  (CEXP*25.0f)             // 1/SIG_DEPTH^2
#define CIND  (CEXP/36.0f)             // 1/SIG_XY^2

// tile geometry: center 32 cols x 16 rows, halo +11 rows below, +-11 cols
#define TX 32
#define TYR 16
#define TROWS 27          // TYR + 11
#define TCOLS 54          // TX + 22
#define TPIX (TROWS*TCOLS) // 1458

#define NCRF 2048         // 2 db-halves x (16x16x4) tiles
#define NSTAT 44
#define NBLK (NCRF + NSTAT)

struct alignas(16) PixH { __half2 rg, bd, y01, y2m; };   // 16 B staged pixel
struct PF { float r,g,b,d,y0,y1,y2,m; };

__device__ __forceinline__ PF unpackPix(PixH p) {
  PF f;
  f.r = __low2float(p.rg);  f.g = __high2float(p.rg);
  f.b = __low2float(p.bd);  f.d = __high2float(p.bd);
  f.y0 = __low2float(p.y01); f.y1 = __high2float(p.y01);
  f.y2 = __low2float(p.y2m); f.m = __high2float(p.y2m);
  return f;
}

// 64-lane sum on the VALU pipe (DPP). Total lands in lane 63.
__device__ __forceinline__ float dpp_sum(float x) {
  x += __int_as_float(__builtin_amdgcn_update_dpp(0, __float_as_int(x), 0x111, 0xf, 0xf, true)); // row_shr:1
  x += __int_as_float(__builtin_amdgcn_update_dpp(0, __float_as_int(x), 0x112, 0xf, 0xf, true)); // row_shr:2
  x += __int_as_float(__builtin_amdgcn_update_dpp(0, __float_as_int(x), 0x114, 0xf, 0xf, true)); // row_shr:4
  x += __int_as_float(__builtin_amdgcn_update_dpp(0, __float_as_int(x), 0x118, 0xf, 0xf, true)); // row_shr:8
  x += __int_as_float(__builtin_amdgcn_update_dpp(0, __float_as_int(x), 0x142, 0xa, 0xf, true)); // row_bcast:15
  x += __int_as_float(__builtin_amdgcn_update_dpp(0, __float_as_int(x), 0x143, 0xc, 0xf, true)); // row_bcast:31
  return x;
}

__device__ __forceinline__ float wave_sum(float x) {
  #pragma unroll
  for (int s = 1; s < 64; s <<= 1) x += __shfl_xor(x, s, 64);
  return x;
}

// coherent cross-XCD read of an atomically-written cell
__device__ __forceinline__ float atomRead(float* p) { return unsafeAtomicAdd(p, 0.0f); }

// ---------------- single fused kernel ----------------
__global__ __launch_bounds__(256, 6) void crf_kernel(
    const float* __restrict__ logit, const int* __restrict__ target,
    const float* __restrict__ image, const float* __restrict__ depth,
    const float* __restrict__ dst,
    float* __restrict__ g_bins, float* __restrict__ g_ce,
    float* __restrict__ rowBand, float* __restrict__ colBand,
    unsigned* __restrict__ done, float* __restrict__ out) {
  __shared__ PixH  tile[TPIX];
  __shared__ float binsS[NBINS];
  __shared__ float redS[12];
  __shared__ bool  lastS;

  int tx = threadIdx.x;
  int bid = blockIdx.x;
  int lane = tx & 63;

  if (bid >= NCRF) {           // ---- stats path: margin band sums of dst ----
    int k = bid - NCRF;
    float s = 0.f;
    if (k < 22) {
      int row = (k < 11) ? k : (234 + k);
      for (int t = tx; t < 2048; t += 256) {
        int b = t >> 9, j = t & 511;
        s += dst[(size_t)b*HW + row*W + j];
      }
    } else {
      int kc = k - 22;
      int col = (kc < 11) ? kc : (490 + kc);
      for (int t = tx; t < 1024; t += 256) {
        int b = t >> 8, i = t & 255;
        s += dst[(size_t)b*HW + i*W + col];
      }
    }
    s = wave_sum(s);
    if (lane == 0) redS[tx >> 6] = s;
    __syncthreads();
    if (tx == 0) {
      float tot = redS[0] + redS[1] + redS[2] + redS[3];
      if (k < 22) unsafeAtomicAdd(&rowBand[k], tot);
      else        unsafeAtomicAdd(&colBand[k - 22], tot);
    }
  } else {                     // ---- crf path ----
    int tileId = bid >> 1;
    int half   = bid & 1;              // 0: db in [-11,-1], 1: db in [1,11]
    int bz  = tileId >> 8;
    int rem = tileId & 255;
    int i0 = (rem >> 4) * TYR;
    int j0 = (rem & 15) * TX;

    const float* lg0 = logit + (size_t)bz*3*HW;
    const float* lg1 = lg0 + HW;
    const float* lg2 = lg0 + 2*HW;
    const float* im0 = image + (size_t)bz*3*HW;
    const float* im1 = im0 + HW;
    const float* im2 = im0 + 2*HW;
    const float* dep = depth + (size_t)bz*HW;
    const float* dsb = dst   + (size_t)bz*HW;
    const int*   tgb = target + (size_t)bz*HW;

    for (int s = tx; s < NBINS; s += 256) binsS[s] = 0.f;

    // staging: global -> LDS (f16 pack) with fused softmax; CE + sum(m) on centers (half 1 only)
    float v0 = 0.f, v1 = 0.f, v2 = 0.f;
    for (int s = tx; s < TPIX; s += 256) {
      int r = s / TCOLS, c = s - r*TCOLS;
      int gi = i0 + r, gj = j0 - 11 + c;
      PixH ph;
      if (gi < H && (unsigned)gj < (unsigned)W) {
        int q = gi*W + gj;
        float l0 = lg0[q], l1 = lg1[q], l2 = lg2[q];
        float mx = fmaxf(l0, fmaxf(l1, l2));
        float e0 = __builtin_amdgcn_exp2f((l0-mx)*LOG2E);
        float e1 = __builtin_amdgcn_exp2f((l1-mx)*LOG2E);
        float e2 = __builtin_amdgcn_exp2f((l2-mx)*LOG2E);
        float S = e0+e1+e2;
        float inv = 1.0f/S;
        float m = dsb[q];
        ph.rg  = __floats2half2_rn(im0[q], im1[q]);
        ph.bd  = __floats2half2_rn(im2[q], dep[q]);
        ph.y01 = __floats2half2_rn(e0*inv, e1*inv);
        ph.y2m = __floats2half2_rn(e2*inv, m);
        if (half && r < TYR && c >= 11 && c < 11+TX) {   // CE only once per tile
          int t = tgb[q];
          float lt = (t==0) ? l0 : ((t==1) ? l1 : l2);
          float lce = mx + __logf(S) - lt;
          float t0 = lce * m;
          v0 += t0;
          v1 += lce - t0;
          v2 += m;
        }
      } else {
        ph.rg = ph.bd = __floats2half2_rn(1e30f, 1e30f);  // +inf sentinel -> kernel = 0
        ph.y01 = ph.y2m = __floats2half2_rn(0.f, 0.f);    // m = 0
      }
      tile[s] = ph;
    }
    __syncthreads();

    // main pair loop: thread owns 2 center rows; half-plane offsets (a>=1), both bins
    int txc = tx & 31, ty = tx >> 5;
    int crow = ty*2;
    int cidx = crow*TCOLS + txc + 11;
    PF c0 = unpackPix(tile[cidx]);
    PF c1 = unpackPix(tile[cidx+TCOLS]);
    int db_base = half ? 1 : -11;

    #pragma unroll 1
    for (int k = 0; k < 11; ++k) {
      int db = db_base + k;
      int nb = cidx + db;
      float lb = CIND * (float)(db*db);
      PF N0 = unpackPix(tile[nb+TCOLS]);     // row crow+1
      #pragma unroll
      for (int a = 1; a <= 11; ++a) {
        PF N1 = unpackPix(tile[nb + (a+1)*TCOLS]);
        float lind = fmaf((float)(a*a), CIND, lb);
        float cc0, cc1;
        {
          float dr = N0.r - c0.r, dg = N0.g - c0.g;
          float dbv = N0.b - c0.b, dd = N0.d - c0.d;
          float rs = fmaf(dr,dr, fmaf(dg,dg, dbv*dbv));
          float a1 = fmaf(rs, CRGB, lind);
          float a2 = (dd*dd)*CDEP;
          float kv = __builtin_amdgcn_exp2f(a1) + __builtin_amdgcn_exp2f(a2);
          float dt = fmaf(N0.y0, c0.y0, fmaf(N0.y1, c0.y1, N0.y2*c0.y2));
          cc0 = kv * (1.0f - dt);
        }
        {
          float dr = N1.r - c1.r, dg = N1.g - c1.g;
          float dbv = N1.b - c1.b, dd = N1.d - c1.d;
          float rs = fmaf(dr,dr, fmaf(dg,dg, dbv*dbv));
          float a1 = fmaf(rs, CRGB, lind);
          float a2 = (dd*dd)*CDEP;
          float kv = __builtin_amdgcn_exp2f(a1) + __builtin_amdgcn_exp2f(a2);
          float dt = fmaf(N1.y0, c1.y0, fmaf(N1.y1, c1.y1, N1.y2*c1.y2));
          cc1 = kv * (1.0f - dt);
        }
        float nd = fmaf(cc1, c1.m, cc0*c0.m);  // -> bin(+a,+db), center m
        float nr = fmaf(cc1, N1.m, cc0*N0.m);  // -> bin(-a,-db), neighbor m
        nd = dpp_sum(nd);
        nr = dpp_sum(nr);
        if (lane == 63) {
          atomicAdd(&binsS[(a+SPAN)*KK + (db+SPAN)], nd);
          atomicAdd(&binsS[(SPAN-a)*KK + (SPAN-db)], nr);
        }
        N0 = N1;
      }
    }
    __syncthreads();

    // flush bins + CE
    for (int s = tx; s < NBINS; s += 256) {
      float v = binsS[s];
      if (v != 0.f) unsafeAtomicAdd(&g_bins[s], v);
    }
    if (half) {
      v0 = dpp_sum(v0); v1 = dpp_sum(v1); v2 = dpp_sum(v2);
      int wv = tx >> 6;
      if (lane == 63) { redS[wv] = v0; redS[4+wv] = v1; redS[8+wv] = v2; }
      __syncthreads();
      if (tx == 0) {
        unsafeAtomicAdd(&g_ce[0], redS[0]+redS[1]+redS[2]+redS[3]);
        unsafeAtomicAdd(&g_ce[1], redS[4]+redS[5]+redS[6]+redS[7]);
        unsafeAtomicAdd(&g_ce[2], redS[8]+redS[9]+redS[10]+redS[11]);
      }
    }
  }

  // ---- epilogue: last block finalizes ----
  __threadfence();
  if (tx == 0) lastS = (atomicAdd(done, 1u) == NBLK - 1);
  __syncthreads();
  if (!lastS) return;

  // shared overlay on tile (all crf use of tile is complete; block-wide synced above)
  float* F      = (float*)tile;
  float* corner = F;          // 484  [22][22]
  float* rb     = F + 484;    // 22
  float* cb     = F + 506;    // 22
  float* TopP   = F + 528;    // 12
  float* BotS   = F + 540;    // 12
  float* LeftP  = F + 552;    // 12
  float* RightS = F + 564;    // 12
  float* TL     = F + 576;    // 144 [12][12]
  float* TR     = F + 720;
  float* BL     = F + 864;
  float* BR     = F + 1008;
  float* redF   = F + 1152;   // 4 + 3

  if (tx < 22) { rb[tx] = atomRead(&rowBand[tx]); cb[tx] = atomRead(&colBand[tx]); }
  if (tx == 32) redF[4] = atomRead(&g_ce[0]);
  if (tx == 33) redF[5] = atomRead(&g_ce[1]);
  if (tx == 34) redF[6] = atomRead(&g_ce[2]);
  for (int t = tx; t < 484; t += 256) {
    int ri = t / 22, ci = t - ri*22;
    int row = (ri < 11) ? ri : (234 + ri);
    int col = (ci < 11) ? ci : (490 + ci);
    float s = 0.f;
    #pragma unroll
    for (int b = 0; b < 4; ++b) s += dst[(size_t)b*HW + row*W + col];
    corner[ri*22 + ci] = s;
  }
  __syncthreads();

  if (tx == 0) { float p=0.f; TopP[0]=0.f;   for (int k=1;k<12;++k){ p += rb[k-1];  TopP[k]=p; } }
  if (tx == 1) { float p=0.f; BotS[0]=0.f;   for (int k=1;k<12;++k){ p += rb[22-k]; BotS[k]=p; } }
  if (tx == 2) { float p=0.f; LeftP[0]=0.f;  for (int k=1;k<12;++k){ p += cb[k-1];  LeftP[k]=p; } }
  if (tx == 3) { float p=0.f; RightS[0]=0.f; for (int k=1;k<12;++k){ p += cb[22-k]; RightS[k]=p; } }
  for (int t = tx; t < 576; t += 256) {
    int tab = t / 144, idx = t - tab*144;
    int a = idx / 12, b = idx - a*12;
    float s = 0.f;
    for (int i = 0; i < a; ++i)
      for (int j = 0; j < b; ++j) {
        int ri = (tab < 2) ? i : (21 - i);
        int ci = (tab & 1) ? (21 - j) : j;
        s += corner[ri*22 + ci];
      }
    if (tab == 0) TL[a*12+b] = s;
    else if (tab == 1) TR[a*12+b] = s;
    else if (tab == 2) BL[a*12+b] = s;
    else BR[a*12+b] = s;
  }
  __syncthreads();

  float S = redF[6];           // total sum of dst
  float esum = 0.f;
  for (int od = tx; od < NBINS; od += 256) {
    int dxp = od / KK, dyp = od - dxp*KK;
    int dx = dxp - SPAN, dy = dyp - SPAN;
    if (dx != 0 && dy != 0) {
      int ax = (dx < 0) ? -dx : 0;
      int bx = (dx > 0) ?  dx : 0;
      int ay = (dy < 0) ? -dy : 0;
      int by = (dy > 0) ?  dy : 0;
      float den = S - TopP[ax] - BotS[bx] - LeftP[ay] - RightS[by]
                + TL[ax*12+ay] + TR[ax*12+by] + BL[bx*12+ay] + BR[bx*12+by];
      esum += atomRead(&g_bins[od]) / den;
    }
  }
  esum = wave_sum(esum);
  if (lane == 0) redF[tx >> 6] = esum;
  __syncthreads();
  if (tx == 0) {
    float E = (redF[0]+redF[1]+redF[2]+redF[3]) / 529.0f;
    float count = S / NPIXF;
    float l1 = redF[4] / NPIXF;
    float l2 = redF[5] / NPIXF;
    out[0] = l1*(1.0f - count) + l2*count;
    out[1] = E;
  }
}

extern "C" void kernel_launch(void* const* d_in, const int* in_sizes, int n_in,
                              void* d_out, int out_size, void* d_ws, size_t ws_size,
                              hipStream_t stream) {
  const float* logit  = (const float*)d_in[0];
  const int*   target = (const int*)  d_in[1];
  const float* image  = (const float*)d_in[2];
  const float* depth  = (const float*)d_in[3];
  const float* dstm   = (const float*)d_in[4];
  float* out = (float*)d_out;

  float* ws      = (float*)d_ws;
  float* g_bins  = ws;               // 529
  float* g_ce    = ws + NBINS;       // 3
  float* rowBand = ws + 532;         // 22
  float* colBand = ws + 554;         // 22
  unsigned* done = (unsigned*)(ws + 576);  // 1

  hipMemsetAsync(ws, 0, 577*sizeof(float), stream);
  crf_kernel<<<NBLK, 256, 0, stream>>>(logit, target, image, depth, dstm,
                                       g_bins, g_ce, rowBand, colBand, done, out);
}

// Round 7
// 268.497 us; speedup vs baseline: 1.2307x; 1.2307x over previous
//
#include <hip/hip_runtime.h>
#include <hip/hip_fp16.h>

#define H 256
#define W 512
#define HW (H*W)
#define NPIXF 524288.0f
#define SPAN 11
#define KK 23
#define NBINS (KK*KK)   // 529

#define LOG2E 1.4426950408889634f
#define CEXP  (-0.7213475204444817f)   // -0.5*log2(e)
#define CRGB  (CEXP*100.0f)            // 1/SIG_RGB^2
#define CDEP  (CEXP*25.0f)             // 1/SIG_DEPTH^2
#define CIND  (CEXP/36.0f)             // 1/SIG_XY^2

// tile geometry: center 32 cols x 16 rows, halo +11 rows below, +-11 cols
#define TX 32
#define TYR 16
#define TROWS 27          // TYR + 11
#define TCOLS 54          // TX + 22
#define TPIX (TROWS*TCOLS) // 1458

#define NCRF 1024         // 16x16x4 tiles, full db range per block
#define NSTAT 44
#define NBLK (NCRF + NSTAT)

struct alignas(16) PixH { __half2 rg, bd, y01, y2m; };   // 16 B staged pixel
struct PF { float r,g,b,d,y0,y1,y2,m; };

__device__ __forceinline__ PF unpackPix(PixH p) {
  PF f;
  f.r = __low2float(p.rg);  f.g = __high2float(p.rg);
  f.b = __low2float(p.bd);  f.d = __high2float(p.bd);
  f.y0 = __low2float(p.y01); f.y1 = __high2float(p.y01);
  f.y2 = __low2float(p.y2m); f.m = __high2float(p.y2m);
  return f;
}

// one step of the 64-lane DPP reduction tree (VALU pipe); ctrl/mask as template
// params because __builtin_amdgcn_update_dpp requires constant integers.
template<int CTRL, int RMASK>
__device__ __forceinline__ float dpp_step(float x) {
  return x + __int_as_float(__builtin_amdgcn_update_dpp(0, __float_as_int(x), CTRL, RMASK, 0xf, true));
}
// full 6-step sum; total lands in lane 63
__device__ __forceinline__ float dpp_sum(float x) {
  x = dpp_step<0x111, 0xf>(x);   // row_shr:1
  x = dpp_step<0x112, 0xf>(x);   // row_shr:2
  x = dpp_step<0x114, 0xf>(x);   // row_shr:4
  x = dpp_step<0x118, 0xf>(x);   // row_shr:8
  x = dpp_step<0x142, 0xa>(x);   // row_bcast:15
  x = dpp_step<0x143, 0xc>(x);   // row_bcast:31
  return x;
}

__device__ __forceinline__ float wave_sum(float x) {
  #pragma unroll
  for (int s = 1; s < 64; s <<= 1) x += __shfl_xor(x, s, 64);
  return x;
}

// coherent cross-XCD read of an atomically-written cell
__device__ __forceinline__ float atomRead(float* p) { return unsafeAtomicAdd(p, 0.0f); }

// ---------------- single fused kernel ----------------
__global__ __launch_bounds__(256, 4) void crf_kernel(
    const float* __restrict__ logit, const int* __restrict__ target,
    const float* __restrict__ image, const float* __restrict__ depth,
    const float* __restrict__ dst,
    float* __restrict__ g_bins, float* __restrict__ g_ce,
    float* __restrict__ rowBand, float* __restrict__ colBand,
    unsigned* __restrict__ done, float* __restrict__ out) {
  __shared__ PixH  tile[TPIX];
  __shared__ float binsS[NBINS];
  __shared__ float redS[12];
  __shared__ bool  lastS;

  int tx = threadIdx.x;
  int bid = blockIdx.x;
  int lane = tx & 63;

  if (bid >= NCRF) {           // ---- stats path: margin band sums of dst ----
    int k = bid - NCRF;
    float s = 0.f;
    if (k < 22) {
      int row = (k < 11) ? k : (234 + k);
      for (int t = tx; t < 2048; t += 256) {
        int b = t >> 9, j = t & 511;
        s += dst[(size_t)b*HW + row*W + j];
      }
    } else {
      int kc = k - 22;
      int col = (kc < 11) ? kc : (490 + kc);
      for (int t = tx; t < 1024; t += 256) {
        int b = t >> 8, i = t & 255;
        s += dst[(size_t)b*HW + i*W + col];
      }
    }
    s = wave_sum(s);
    if (lane == 0) redS[tx >> 6] = s;
    __syncthreads();
    if (tx == 0) {
      float tot = redS[0] + redS[1] + redS[2] + redS[3];
      if (k < 22) unsafeAtomicAdd(&rowBand[k], tot);
      else        unsafeAtomicAdd(&colBand[k - 22], tot);
    }
  } else {                     // ---- crf path ----
    int bz  = bid >> 8;
    int rem = bid & 255;
    int i0 = (rem >> 4) * TYR;
    int j0 = (rem & 15) * TX;

    const float* lg0 = logit + (size_t)bz*3*HW;
    const float* lg1 = lg0 + HW;
    const float* lg2 = lg0 + 2*HW;
    const float* im0 = image + (size_t)bz*3*HW;
    const float* im1 = im0 + HW;
    const float* im2 = im0 + 2*HW;
    const float* dep = depth + (size_t)bz*HW;
    const float* dsb = dst   + (size_t)bz*HW;
    const int*   tgb = target + (size_t)bz*HW;

    for (int s = tx; s < NBINS; s += 256) binsS[s] = 0.f;

    // staging: global -> LDS (f16 pack) with fused softmax; CE + sum(m) on centers
    float v0 = 0.f, v1 = 0.f, v2 = 0.f;
    for (int s = tx; s < TPIX; s += 256) {
      int r = s / TCOLS, c = s - r*TCOLS;
      int gi = i0 + r, gj = j0 - 11 + c;
      PixH ph;
      if (gi < H && (unsigned)gj < (unsigned)W) {
        int q = gi*W + gj;
        float l0 = lg0[q], l1 = lg1[q], l2 = lg2[q];
        float mx = fmaxf(l0, fmaxf(l1, l2));
        float e0 = __builtin_amdgcn_exp2f((l0-mx)*LOG2E);
        float e1 = __builtin_amdgcn_exp2f((l1-mx)*LOG2E);
        float e2 = __builtin_amdgcn_exp2f((l2-mx)*LOG2E);
        float S = e0+e1+e2;
        float inv = 1.0f/S;
        float m = dsb[q];
        ph.rg  = __floats2half2_rn(im0[q], im1[q]);
        ph.bd  = __floats2half2_rn(im2[q], dep[q]);
        ph.y01 = __floats2half2_rn(e0*inv, e1*inv);
        ph.y2m = __floats2half2_rn(e2*inv, m);
        if (r < TYR && c >= 11 && c < 11+TX) {   // center pixel
          int t = tgb[q];
          float lt = (t==0) ? l0 : ((t==1) ? l1 : l2);
          float lce = mx + __logf(S) - lt;
          float t0 = lce * m;
          v0 += t0;
          v1 += lce - t0;
          v2 += m;
        }
      } else {
        ph.rg = ph.bd = __floats2half2_rn(1e30f, 1e30f);  // +inf sentinel -> kernel = 0
        ph.y01 = ph.y2m = __floats2half2_rn(0.f, 0.f);    // m = 0
      }
      tile[s] = ph;
    }
    __syncthreads();

    // main pair loop: thread owns 2 center rows; half-plane offsets (a>=1), both bins
    int txc = tx & 31, ty = tx >> 5;
    int crow = ty*2;
    int cidx = crow*TCOLS + txc + 11;
    PF c0 = unpackPix(tile[cidx]);
    PF c1 = unpackPix(tile[cidx+TCOLS]);

    #pragma unroll 1
    for (int bi = 0; bi < 22; ++bi) {
      int db = bi - ((bi < 11) ? 11 : 10);   // -11..-1, 1..11
      int nb = cidx + db;
      float lb = CIND * (float)(db*db);
      float ndv[11], nrv[11];

      // ---- phase 1: compute 22 scalars, no cross-lane ops (deep ILP) ----
      PF N0 = unpackPix(tile[nb+TCOLS]);     // row crow+1
      #pragma unroll
      for (int a = 1; a <= 11; ++a) {
        PF N1 = unpackPix(tile[nb + (a+1)*TCOLS]);
        float lind = fmaf((float)(a*a), CIND, lb);
        float cc0, cc1;
        {
          float dr = N0.r - c0.r, dg = N0.g - c0.g;
          float dbv = N0.b - c0.b, dd = N0.d - c0.d;
          float rs = fmaf(dr,dr, fmaf(dg,dg, dbv*dbv));
          float a1 = fmaf(rs, CRGB, lind);
          float a2 = (dd*dd)*CDEP;
          float kv = __builtin_amdgcn_exp2f(a1) + __builtin_amdgcn_exp2f(a2);
          float dt = fmaf(N0.y0, c0.y0, fmaf(N0.y1, c0.y1, N0.y2*c0.y2));
          cc0 = kv * (1.0f - dt);
        }
        {
          float dr = N1.r - c1.r, dg = N1.g - c1.g;
          float dbv = N1.b - c1.b, dd = N1.d - c1.d;
          float rs = fmaf(dr,dr, fmaf(dg,dg, dbv*dbv));
          float a1 = fmaf(rs, CRGB, lind);
          float a2 = (dd*dd)*CDEP;
          float kv = __builtin_amdgcn_exp2f(a1) + __builtin_amdgcn_exp2f(a2);
          float dt = fmaf(N1.y0, c1.y0, fmaf(N1.y1, c1.y1, N1.y2*c1.y2));
          cc1 = kv * (1.0f - dt);
        }
        ndv[a-1] = fmaf(cc1, c1.m, cc0*c0.m);  // -> bin(+a,+db), center m
        nrv[a-1] = fmaf(cc1, N1.m, cc0*N0.m);  // -> bin(-a,-db), neighbor m
        N0 = N1;
      }

      // ---- phase 2: 22 independent DPP chains, interleaved by the scheduler ----
      #pragma unroll
      for (int a = 0; a < 11; ++a) { ndv[a] = dpp_sum(ndv[a]); nrv[a] = dpp_sum(nrv[a]); }

      // ---- phase 3: lane 63 commits 22 LDS atomics in one burst ----
      if (lane == 63) {
        #pragma unroll
        for (int a = 0; a < 11; ++a) {
          atomicAdd(&binsS[(a+1+SPAN)*KK + (db+SPAN)], ndv[a]);
          atomicAdd(&binsS[(SPAN-(a+1))*KK + (SPAN-db)], nrv[a]);
        }
      }
    }
    __syncthreads();

    // flush bins + CE
    for (int s = tx; s < NBINS; s += 256) {
      float v = binsS[s];
      if (v != 0.f) unsafeAtomicAdd(&g_bins[s], v);
    }
    v0 = dpp_sum(v0); v1 = dpp_sum(v1); v2 = dpp_sum(v2);
    int wv = tx >> 6;
    if (lane == 63) { redS[wv] = v0; redS[4+wv] = v1; redS[8+wv] = v2; }
    __syncthreads();
    if (tx == 0) {
      unsafeAtomicAdd(&g_ce[0], redS[0]+redS[1]+redS[2]+redS[3]);
      unsafeAtomicAdd(&g_ce[1], redS[4]+redS[5]+redS[6]+redS[7]);
      unsafeAtomicAdd(&g_ce[2], redS[8]+redS[9]+redS[10]+redS[11]);
    }
  }

  // ---- epilogue: last block finalizes ----
  __threadfence();
  if (tx == 0) lastS = (atomicAdd(done, 1u) == NBLK - 1);
  __syncthreads();
  if (!lastS) return;

  // shared overlay on tile (all crf use of tile is complete; block-wide synced above)
  float* F      = (float*)tile;
  float* corner = F;          // 484  [22][22]
  float* rb     = F + 484;    // 22
  float* cb     = F + 506;    // 22
  float* TopP   = F + 528;    // 12
  float* BotS   = F + 540;    // 12
  float* LeftP  = F + 552;    // 12
  float* RightS = F + 564;    // 12
  float* TL     = F + 576;    // 144 [12][12]
  float* TR     = F + 720;
  float* BL     = F + 864;
  float* BR     = F + 1008;
  float* redF   = F + 1152;   // 4 + 3

  if (tx < 22) { rb[tx] = atomRead(&rowBand[tx]); cb[tx] = atomRead(&colBand[tx]); }
  if (tx == 32) redF[4] = atomRead(&g_ce[0]);
  if (tx == 33) redF[5] = atomRead(&g_ce[1]);
  if (tx == 34) redF[6] = atomRead(&g_ce[2]);
  for (int t = tx; t < 484; t += 256) {
    int ri = t / 22, ci = t - ri*22;
    int row = (ri < 11) ? ri : (234 + ri);
    int col = (ci < 11) ? ci : (490 + ci);
    float s = 0.f;
    #pragma unroll
    for (int b = 0; b < 4; ++b) s += dst[(size_t)b*HW + row*W + col];
    corner[ri*22 + ci] = s;
  }
  __syncthreads();

  if (tx == 0) { float p=0.f; TopP[0]=0.f;   for (int k=1;k<12;++k){ p += rb[k-1];  TopP[k]=p; } }
  if (tx == 1) { float p=0.f; BotS[0]=0.f;   for (int k=1;k<12;++k){ p += rb[22-k]; BotS[k]=p; } }
  if (tx == 2) { float p=0.f; LeftP[0]=0.f;  for (int k=1;k<12;++k){ p += cb[k-1];  LeftP[k]=p; } }
  if (tx == 3) { float p=0.f; RightS[0]=0.f; for (int k=1;k<12;++k){ p += cb[22-k]; RightS[k]=p; } }
  for (int t = tx; t < 576; t += 256) {
    int tab = t / 144, idx = t - tab*144;
    int a = idx / 12, b = idx - a*12;
    float s = 0.f;
    for (int i = 0; i < a; ++i)
      for (int j = 0; j < b; ++j) {
        int ri = (tab < 2) ? i : (21 - i);
        int ci = (tab & 1) ? (21 - j) : j;
        s += corner[ri*22 + ci];
      }
    if (tab == 0) TL[a*12+b] = s;
    else if (tab == 1) TR[a*12+b] = s;
    else if (tab == 2) BL[a*12+b] = s;
    else BR[a*12+b] = s;
  }
  __syncthreads();

  float S = redF[6];           // total sum of dst
  float esum = 0.f;
  for (int od = tx; od < NBINS; od += 256) {
    int dxp = od / KK, dyp = od - dxp*KK;
    int dx = dxp - SPAN, dy = dyp - SPAN;
    if (dx != 0 && dy != 0) {
      int ax = (dx < 0) ? -dx : 0;
      int bx = (dx > 0) ?  dx : 0;
      int ay = (dy < 0) ? -dy : 0;
      int by = (dy > 0) ?  dy : 0;
      float den = S - TopP[ax] - BotS[bx] - LeftP[ay] - RightS[by]
                + TL[ax*12+ay] + TR[ax*12+by] + BL[bx*12+ay] + BR[bx*12+by];
      esum += atomRead(&g_bins[od]) / den;
    }
  }
  esum = wave_sum(esum);
  if (lane == 0) redF[tx >> 6] = esum;
  __syncthreads();
  if (tx == 0) {
    float E = (redF[0]+redF[1]+redF[2]+redF[3]) / 529.0f;
    float count = S / NPIXF;
    float l1 = redF[4] / NPIXF;
    float l2 = redF[5] / NPIXF;
    out[0] = l1*(1.0f - count) + l2*count;
    out[1] = E;
  }
}

extern "C" void kernel_launch(void* const* d_in, const int* in_sizes, int n_in,
                              void* d_out, int out_size, void* d_ws, size_t ws_size,
                              hipStream_t stream) {
  const float* logit  = (const float*)d_in[0];
  const int*   target = (const int*)  d_in[1];
  const float* image  = (const float*)d_in[2];
  const float* depth  = (const float*)d_in[3];
  const float* dstm   = (const float*)d_in[4];
  float* out = (float*)d_out;

  float* ws      = (float*)d_ws;
  float* g_bins  = ws;               // 529
  float* g_ce    = ws + NBINS;       // 3
  float* rowBand = ws + 532;         // 22
  float* colBand = ws + 554;         // 22
  unsigned* done = (unsigned*)(ws + 576);  // 1

  (void)hipMemsetAsync(ws, 0, 577*sizeof(float), stream);
  crf_kernel<<<NBLK, 256, 0, stream>>>(logit, target, image, depth, dstm,
                                       g_bins, g_ce, rowBand, colBand, done, out);
}